// Round 19
// baseline (231.869 us; speedup 1.0000x reference)
//
#include <hip/hip_runtime.h>
#include <math.h>

#define Ydim 384
#define Xdim 512
#define NPIX (Ydim * Xdim)
#define EPS 1e-4
#define PPB 128
#define NITER (PPB / 32)

__device__ __forceinline__ double fast_rcp64(double d) {
    double r = (double)__builtin_amdgcn_rcpf((float)d);
    r = r * (2.0 - d * r);
    r = r * (2.0 - d * r);
    return r;
}

// ---------------- Kernel 1: cost only ----------------
// 32 pixels/block, 8 lanes/pixel, 2-row streamed gather (VGPR-slim, ~60).
// No solve tail, no fp64 pressure, no half-wave idle: pure gather+SSD at
// max TLP (launch_bounds(256,8) -> 8 waves/SIMD capable; 24 blocks/CU).
// Writes cost planar [9][NPIX] so the solve kernel reads coalesced.
__global__ __launch_bounds__(256, 8) void qf_cost_kernel(
    const float* __restrict__ feat0,
    const float* __restrict__ feat1,
    const float* __restrict__ flow,
    float* __restrict__ cost)   // [9][NPIX]
{
    __shared__ float cost_lds[32 * 9];

    const int t   = threadIdx.x;
    const int g   = t >> 3;
    const int sub = t & 7;
    const int pix = blockIdx.x * 32 + g;
    const int y = pix >> 9;
    const int x = pix & (Xdim - 1);

    const float u = flow[pix * 3 + 0];
    const float v = flow[pix * 3 + 1];
    const float4 f0 = *(const float4*)(feat0 + (size_t)pix * 32 + sub * 4);

    const float pxc = (float)x + u;
    const float pyc = (float)y + v;

    int   c0[3], c1[3], r0[3], r1[3];
    float wx[3], wy[3];
#pragma unroll
    for (int j = 0; j < 3; ++j) {
        float px = pxc + (float)(j - 1);
        float fx = floorf(px);
        wx[j] = px - fx;
        int xi = min(max((int)fx, 0), Xdim - 1);
        c0[j] = xi;
        c1[j] = min(xi + 1, Xdim - 1);
        float py = pyc + (float)(j - 1);
        float fy = floorf(py);
        wy[j] = py - fy;
        int yi = min(max((int)fy, 0), Ydim - 1);
        r0[j] = yi;
        r1[j] = min(yi + 1, Ydim - 1);
    }

    float cacc[9];
    const bool fast = (c1[0] == c0[1]) & (c1[1] == c0[2])
                    & (r1[0] == r0[1]) & (r1[1] == r0[2]);

    if (fast) {
        const int cols[4] = {c0[0], c0[1], c0[2], c1[2]};
        const int rows[4] = {r0[0], r0[1], r0[2], r1[2]};
        float4 Fp[4], Fc[4];
        {
            const float* rb = feat1 + ((size_t)rows[0] * Xdim) * 32 + sub * 4;
#pragma unroll
            for (int c = 0; c < 4; ++c)
                Fp[c] = *(const float4*)(rb + (size_t)cols[c] * 32);
        }
#pragma unroll
        for (int i = 0; i < 3; ++i) {
            const float* rb = feat1 + ((size_t)rows[i + 1] * Xdim) * 32 + sub * 4;
#pragma unroll
            for (int c = 0; c < 4; ++c)
                Fc[c] = *(const float4*)(rb + (size_t)cols[c] * 32);
            float wyv = wy[i], omwy = 1.f - wyv;
#pragma unroll
            for (int j = 0; j < 3; ++j) {
                float wxv = wx[j], omwx = 1.f - wxv;
                float w00 = omwx * omwy, w01 = wxv * omwy;
                float w10 = omwx * wyv,  w11 = wxv * wyv;
                float4 a = Fp[j], b = Fp[j + 1], c = Fc[j], d = Fc[j + 1];
                float dx = f0.x - (a.x * w00 + b.x * w01 + c.x * w10 + d.x * w11);
                float dy = f0.y - (a.y * w00 + b.y * w01 + c.y * w10 + d.y * w11);
                float dz = f0.z - (a.z * w00 + b.z * w01 + c.z * w10 + d.z * w11);
                float dw = f0.w - (a.w * w00 + b.w * w01 + c.w * w10 + d.w * w11);
                cacc[i * 3 + j] = dx * dx + dy * dy + dz * dz + dw * dw;
            }
#pragma unroll
            for (int c = 0; c < 4; ++c) Fp[c] = Fc[c];
        }
    } else {
#pragma unroll
        for (int i = 0; i < 3; ++i) {
            float wyv = wy[i], omwy = 1.f - wyv;
            int rb0 = r0[i] * (Xdim * 32);
            int rb1 = r1[i] * (Xdim * 32);
#pragma unroll
            for (int j = 0; j < 3; ++j) {
                const float4 f00 = *(const float4*)(feat1 + rb0 + c0[j] * 32 + sub * 4);
                const float4 f01 = *(const float4*)(feat1 + rb0 + c1[j] * 32 + sub * 4);
                const float4 f10 = *(const float4*)(feat1 + rb1 + c0[j] * 32 + sub * 4);
                const float4 f11 = *(const float4*)(feat1 + rb1 + c1[j] * 32 + sub * 4);
                float wxv = wx[j], omwx = 1.f - wxv;
                float w00 = omwx * omwy, w01 = wxv * omwy;
                float w10 = omwx * wyv,  w11 = wxv * wyv;
                float dx = f0.x - (f00.x * w00 + f01.x * w01 + f10.x * w10 + f11.x * w11);
                float dy = f0.y - (f00.y * w00 + f01.y * w01 + f10.y * w10 + f11.y * w11);
                float dz = f0.z - (f00.z * w00 + f01.z * w01 + f10.z * w10 + f11.z * w11);
                float dw = f0.w - (f00.w * w00 + f01.w * w01 + f10.w * w10 + f11.w * w11);
                cacc[i * 3 + j] = dx * dx + dy * dy + dz * dz + dw * dw;
            }
        }
    }

#pragma unroll
    for (int m = 1; m <= 4; m <<= 1) {
#pragma unroll
        for (int k = 0; k < 9; ++k)
            cacc[k] += __shfl_xor(cacc[k], m);
    }
    if (sub == 0) {
#pragma unroll
        for (int k = 0; k < 9; ++k)
            cost_lds[g * 9 + k] = cacc[k];
    }
    __syncthreads();

    // Planar write: for fixed k, 32 consecutive pixels = 128B contiguous.
    // LDS read stride 9 (odd) over p -> conflict-free.
    {
        const int k = t >> 5, p = t & 31;             // k = 0..7
        cost[(size_t)k * NPIX + blockIdx.x * 32 + p] = cost_lds[p * 9 + k];
        if (t < 32)
            cost[(size_t)8 * NPIX + blockIdx.x * 32 + t] = cost_lds[t * 9 + 8];
    }
}

// ---------------- Kernel 2: softmax + 6x6 solve ----------------
// 1 thread per pixel, full 64-lane waves, coalesced planar cost reads.
// Numerics identical to the fused kernel's solve phase.
__global__ __launch_bounds__(256, 4) void qf_solve_kernel(
    const float* __restrict__ cost,   // [9][NPIX]
    float* __restrict__ out)          // [NPIX][6]
{
    const int pix = blockIdx.x * 256 + threadIdx.x;

    float c[9];
#pragma unroll
    for (int k = 0; k < 9; ++k) c[k] = cost[(size_t)k * NPIX + pix];

    float cmin = c[0];
#pragma unroll
    for (int k = 1; k < 9; ++k) cmin = fminf(cmin, c[k]);

    float e[9], sumf = 0.f;
#pragma unroll
    for (int k = 0; k < 9; ++k) {
        e[k] = expf(cmin - c[k]);
        sumf += e[k];
    }
    float invs = 1.f / sumf;

    float w[9], q[9];
#pragma unroll
    for (int k = 0; k < 9; ++k) {
        w[k] = e[k] * invs;
        q[k] = w[k] * c[k];
    }

    float sc0 = w[0] + w[3] + w[6], sc2 = w[2] + w[5] + w[8];
    float sr0 = w[0] + w[1] + w[2], sr2 = w[6] + w[7] + w[8];
    float S10 = sc2 - sc0, S20 = sc2 + sc0;
    float S01 = sr2 - sr0, S02 = sr2 + sr0;
    float S11 = (w[0] + w[8]) - (w[2] + w[6]);
    float S21 = (w[6] + w[8]) - (w[0] + w[2]);
    float S12 = (w[2] + w[8]) - (w[0] + w[6]);
    float S22 = w[0] + w[2] + w[6] + w[8];
    float S00 = sr0 + w[3] + w[4] + w[5] + sr2;

    float qc0 = q[0] + q[3] + q[6], qc2 = q[2] + q[5] + q[8];
    float qr0 = q[0] + q[1] + q[2], qr2 = q[6] + q[7] + q[8];
    float T10 = qc2 - qc0, T20 = qc2 + qc0;
    float T01 = qr2 - qr0, T02 = qr2 + qr0;
    float T11 = (q[0] + q[8]) - (q[2] + q[6]);
    float T00 = qr0 + q[3] + q[4] + q[5] + qr2;

    double M[6][6], rhs[6], ip[6];
    M[0][0] = (double)S20 + EPS; M[0][1] = S22; M[0][2] = S11; M[0][3] = S10; M[0][4] = S21; M[0][5] = S20;
    M[1][1] = (double)S02 + EPS; M[1][2] = S11; M[1][3] = S12; M[1][4] = S01; M[1][5] = S02;
    M[2][2] = (double)S22 + EPS; M[2][3] = S21; M[2][4] = S12; M[2][5] = S11;
    M[3][3] = (double)S20 + EPS; M[3][4] = S11; M[3][5] = S10;
    M[4][4] = (double)S02 + EPS; M[4][5] = S01;
    M[5][5] = (double)S00 + EPS;
    rhs[0] = T20; rhs[1] = T02; rhs[2] = T11; rhs[3] = T10; rhs[4] = T01; rhs[5] = T00;

#pragma unroll
    for (int p = 0; p < 6; ++p) {
        ip[p] = fast_rcp64(M[p][p]);
#pragma unroll
        for (int r = p + 1; r < 6; ++r) {
            double f = M[p][r] * ip[p];
#pragma unroll
            for (int cc = r; cc < 6; ++cc)
                M[r][cc] -= f * M[p][cc];
            rhs[r] -= f * rhs[p];
        }
    }
    double sol[6];
#pragma unroll
    for (int p = 5; p >= 0; --p) {
        double s2 = rhs[p];
#pragma unroll
        for (int cc = p + 1; cc < 6; ++cc) s2 -= M[p][cc] * sol[cc];
        sol[p] = s2 * ip[p];
    }

#pragma unroll
    for (int i = 0; i < 6; ++i) out[(size_t)pix * 6 + i] = (float)sol[i];
}

// ---------------- Fallback: R15 fused kernel (if d_ws too small) ----------------
__global__ __launch_bounds__(256, 2) void qf_fused_kernel(
    const float* __restrict__ feat0,
    const float* __restrict__ feat1,
    const float* __restrict__ flow,
    float* __restrict__ out)
{
    __shared__ float cost_lds[PPB * 9];

    const int t   = threadIdx.x;
    const int g   = t >> 3;
    const int sub = t & 7;

#pragma unroll 1
    for (int it = 0; it < NITER; ++it) {
        const int pb  = it * 32 + g;
        const int pix = blockIdx.x * PPB + pb;
        const int y = pix >> 9;
        const int x = pix & (Xdim - 1);

        const float u = flow[pix * 3 + 0];
        const float v = flow[pix * 3 + 1];
        const float4 f0 = *(const float4*)(feat0 + (size_t)pix * 32 + sub * 4);

        const float pxc = (float)x + u;
        const float pyc = (float)y + v;

        int   c0[3], c1[3], r0[3], r1[3];
        float wx[3], wy[3];
#pragma unroll
        for (int j = 0; j < 3; ++j) {
            float px = pxc + (float)(j - 1);
            float fx = floorf(px);
            wx[j] = px - fx;
            int xi = min(max((int)fx, 0), Xdim - 1);
            c0[j] = xi;
            c1[j] = min(xi + 1, Xdim - 1);
            float py = pyc + (float)(j - 1);
            float fy = floorf(py);
            wy[j] = py - fy;
            int yi = min(max((int)fy, 0), Ydim - 1);
            r0[j] = yi;
            r1[j] = min(yi + 1, Ydim - 1);
        }

        float cacc[9];
        const bool fast = (c1[0] == c0[1]) & (c1[1] == c0[2])
                        & (r1[0] == r0[1]) & (r1[1] == r0[2]);

        if (fast) {
            const int cols[4] = {c0[0], c0[1], c0[2], c1[2]};
            const int rows[4] = {r0[0], r0[1], r0[2], r1[2]};
            float4 F[4][4];
#pragma unroll
            for (int r = 0; r < 4; ++r) {
                const float* rb = feat1 + ((size_t)rows[r] * Xdim) * 32 + sub * 4;
#pragma unroll
                for (int c = 0; c < 4; ++c)
                    F[r][c] = *(const float4*)(rb + (size_t)cols[c] * 32);
            }
#pragma unroll
            for (int r = 0; r < 4; ++r)
#pragma unroll
                for (int c = 0; c < 4; ++c)
                    asm volatile("" : "+v"(F[r][c].x), "+v"(F[r][c].y),
                                      "+v"(F[r][c].z), "+v"(F[r][c].w));
#pragma unroll
            for (int i = 0; i < 3; ++i) {
                float wyv = wy[i], omwy = 1.f - wyv;
#pragma unroll
                for (int j = 0; j < 3; ++j) {
                    float wxv = wx[j], omwx = 1.f - wxv;
                    float w00 = omwx * omwy, w01 = wxv * omwy;
                    float w10 = omwx * wyv,  w11 = wxv * wyv;
                    float4 a = F[i][j], b = F[i][j + 1], c = F[i + 1][j], d = F[i + 1][j + 1];
                    float dx = f0.x - (a.x * w00 + b.x * w01 + c.x * w10 + d.x * w11);
                    float dy = f0.y - (a.y * w00 + b.y * w01 + c.y * w10 + d.y * w11);
                    float dz = f0.z - (a.z * w00 + b.z * w01 + c.z * w10 + d.z * w11);
                    float dw = f0.w - (a.w * w00 + b.w * w01 + c.w * w10 + d.w * w11);
                    cacc[i * 3 + j] = dx * dx + dy * dy + dz * dz + dw * dw;
                }
            }
        } else {
#pragma unroll
            for (int i = 0; i < 3; ++i) {
                float wyv = wy[i], omwy = 1.f - wyv;
                int rb0 = r0[i] * (Xdim * 32);
                int rb1 = r1[i] * (Xdim * 32);
#pragma unroll
                for (int j = 0; j < 3; ++j) {
                    const float4 f00 = *(const float4*)(feat1 + rb0 + c0[j] * 32 + sub * 4);
                    const float4 f01 = *(const float4*)(feat1 + rb0 + c1[j] * 32 + sub * 4);
                    const float4 f10 = *(const float4*)(feat1 + rb1 + c0[j] * 32 + sub * 4);
                    const float4 f11 = *(const float4*)(feat1 + rb1 + c1[j] * 32 + sub * 4);
                    float wxv = wx[j], omwx = 1.f - wxv;
                    float w00 = omwx * omwy, w01 = wxv * omwy;
                    float w10 = omwx * wyv,  w11 = wxv * wyv;
                    float dx = f0.x - (f00.x * w00 + f01.x * w01 + f10.x * w10 + f11.x * w11);
                    float dy = f0.y - (f00.y * w00 + f01.y * w01 + f10.y * w10 + f11.y * w11);
                    float dz = f0.z - (f00.z * w00 + f01.z * w01 + f10.z * w10 + f11.z * w11);
                    float dw = f0.w - (f00.w * w00 + f01.w * w01 + f10.w * w10 + f11.w * w11);
                    cacc[i * 3 + j] = dx * dx + dy * dy + dz * dz + dw * dw;
                }
            }
        }

#pragma unroll
        for (int m = 1; m <= 4; m <<= 1) {
#pragma unroll
            for (int k = 0; k < 9; ++k)
                cacc[k] += __shfl_xor(cacc[k], m);
        }
        if (sub == 0) {
#pragma unroll
            for (int k = 0; k < 9; ++k)
                cost_lds[pb * 9 + k] = cacc[k];
        }
    }
    __syncthreads();

    const int lane = t & 63;
    if (lane < 32) {
        const int pb = (t >> 6) * 32 + lane;

        float c[9];
#pragma unroll
        for (int k = 0; k < 9; ++k) c[k] = cost_lds[pb * 9 + k];

        float cmin = c[0];
#pragma unroll
        for (int k = 1; k < 9; ++k) cmin = fminf(cmin, c[k]);

        float e[9], sumf = 0.f;
#pragma unroll
        for (int k = 0; k < 9; ++k) {
            e[k] = expf(cmin - c[k]);
            sumf += e[k];
        }
        float invs = 1.f / sumf;

        float w[9], q[9];
#pragma unroll
        for (int k = 0; k < 9; ++k) {
            w[k] = e[k] * invs;
            q[k] = w[k] * c[k];
        }

        float sc0 = w[0] + w[3] + w[6], sc2 = w[2] + w[5] + w[8];
        float sr0 = w[0] + w[1] + w[2], sr2 = w[6] + w[7] + w[8];
        float S10 = sc2 - sc0, S20 = sc2 + sc0;
        float S01 = sr2 - sr0, S02 = sr2 + sr0;
        float S11 = (w[0] + w[8]) - (w[2] + w[6]);
        float S21 = (w[6] + w[8]) - (w[0] + w[2]);
        float S12 = (w[2] + w[8]) - (w[0] + w[6]);
        float S22 = w[0] + w[2] + w[6] + w[8];
        float S00 = sr0 + w[3] + w[4] + w[5] + sr2;

        float qc0 = q[0] + q[3] + q[6], qc2 = q[2] + q[5] + q[8];
        float qr0 = q[0] + q[1] + q[2], qr2 = q[6] + q[7] + q[8];
        float T10 = qc2 - qc0, T20 = qc2 + qc0;
        float T01 = qr2 - qr0, T02 = qr2 + qr0;
        float T11 = (q[0] + q[8]) - (q[2] + q[6]);
        float T00 = qr0 + q[3] + q[4] + q[5] + qr2;

        double M[6][6], rhs[6], ip[6];
        M[0][0] = (double)S20 + EPS; M[0][1] = S22; M[0][2] = S11; M[0][3] = S10; M[0][4] = S21; M[0][5] = S20;
        M[1][1] = (double)S02 + EPS; M[1][2] = S11; M[1][3] = S12; M[1][4] = S01; M[1][5] = S02;
        M[2][2] = (double)S22 + EPS; M[2][3] = S21; M[2][4] = S12; M[2][5] = S11;
        M[3][3] = (double)S20 + EPS; M[3][4] = S11; M[3][5] = S10;
        M[4][4] = (double)S02 + EPS; M[4][5] = S01;
        M[5][5] = (double)S00 + EPS;
        rhs[0] = T20; rhs[1] = T02; rhs[2] = T11; rhs[3] = T10; rhs[4] = T01; rhs[5] = T00;

#pragma unroll
        for (int p = 0; p < 6; ++p) {
            ip[p] = fast_rcp64(M[p][p]);
#pragma unroll
            for (int r = p + 1; r < 6; ++r) {
                double f = M[p][r] * ip[p];
#pragma unroll
                for (int cc = r; cc < 6; ++cc)
                    M[r][cc] -= f * M[p][cc];
                rhs[r] -= f * rhs[p];
            }
        }
        double sol[6];
#pragma unroll
        for (int p = 5; p >= 0; --p) {
            double s2 = rhs[p];
#pragma unroll
            for (int cc = p + 1; cc < 6; ++cc) s2 -= M[p][cc] * sol[cc];
            sol[p] = s2 * ip[p];
        }

        const int opix = blockIdx.x * PPB + pb;
#pragma unroll
        for (int i = 0; i < 6; ++i) out[(size_t)opix * 6 + i] = (float)sol[i];
    }
}

extern "C" void kernel_launch(void* const* d_in, const int* in_sizes, int n_in,
                              void* d_out, int out_size, void* d_ws, size_t ws_size,
                              hipStream_t stream) {
    const float* feat0 = (const float*)d_in[0];
    const float* feat1 = (const float*)d_in[1];
    const float* flow  = (const float*)d_in[2];
    float* out = (float*)d_out;

    const size_t need = (size_t)9 * NPIX * sizeof(float);   // 7.08 MB
    if (d_ws != nullptr && ws_size >= need) {
        float* cost = (float*)d_ws;
        qf_cost_kernel<<<dim3(NPIX / 32), dim3(256), 0, stream>>>(feat0, feat1, flow, cost);
        qf_solve_kernel<<<dim3(NPIX / 256), dim3(256), 0, stream>>>(cost, out);
    } else {
        qf_fused_kernel<<<dim3(NPIX / PPB), dim3(256), 0, stream>>>(feat0, feat1, flow, out);
    }
}

// Round 20
// 227.590 us; speedup vs baseline: 1.0188x; 1.0188x over previous
//
#include <hip/hip_runtime.h>
#include <math.h>

#define Ydim 384
#define Xdim 512
#define NPIX (Ydim * Xdim)
#define EPS 1e-4
#define PPB 128
#define NITER (PPB / 32)
#define NBLK (NPIX / 32)          // 6144 cost blocks, divisible by 8

__device__ __forceinline__ double fast_rcp64(double d) {
    double r = (double)__builtin_amdgcn_rcpf((float)d);
    r = r * (2.0 - d * r);
    r = r * (2.0 - d * r);
    return r;
}

// ---------------- Kernel 1: cost only, XCD-swizzled ----------------
// R19 measured: 73% occupancy but FETCH 169 MB (6x amplification) and
// 155us -- blocks round-robin across 8 XCDs, so each XCD's private 4MB L2
// sees the whole ~100-row working stripe and thrashes. Fix: bijective
// XCD swizzle (NBLK%8==0): each XCD owns a contiguous 48-row band; its
// ~180 resident blocks cover ~11 rows (~1-2MB) -> fits L2.
__global__ __launch_bounds__(256, 8) void qf_cost_kernel(
    const float* __restrict__ feat0,
    const float* __restrict__ feat1,
    const float* __restrict__ flow,
    float* __restrict__ cost)   // [9][NPIX]
{
    __shared__ float cost_lds[32 * 9];

    const int t   = threadIdx.x;
    const int g   = t >> 3;
    const int sub = t & 7;
    // bijective XCD-aware swizzle: xcd = bid%8 gets contiguous chunk
    const int bid = blockIdx.x;
    const int swz = (bid & 7) * (NBLK >> 3) + (bid >> 3);
    const int pix = swz * 32 + g;
    const int y = pix >> 9;
    const int x = pix & (Xdim - 1);

    const float u = flow[pix * 3 + 0];
    const float v = flow[pix * 3 + 1];
    const float4 f0 = *(const float4*)(feat0 + (size_t)pix * 32 + sub * 4);

    const float pxc = (float)x + u;
    const float pyc = (float)y + v;

    int   c0[3], c1[3], r0[3], r1[3];
    float wx[3], wy[3];
#pragma unroll
    for (int j = 0; j < 3; ++j) {
        float px = pxc + (float)(j - 1);
        float fx = floorf(px);
        wx[j] = px - fx;
        int xi = min(max((int)fx, 0), Xdim - 1);
        c0[j] = xi;
        c1[j] = min(xi + 1, Xdim - 1);
        float py = pyc + (float)(j - 1);
        float fy = floorf(py);
        wy[j] = py - fy;
        int yi = min(max((int)fy, 0), Ydim - 1);
        r0[j] = yi;
        r1[j] = min(yi + 1, Ydim - 1);
    }

    float cacc[9];
    const bool fast = (c1[0] == c0[1]) & (c1[1] == c0[2])
                    & (r1[0] == r0[1]) & (r1[1] == r0[2]);

    if (fast) {
        const int cols[4] = {c0[0], c0[1], c0[2], c1[2]};
        const int rows[4] = {r0[0], r0[1], r0[2], r1[2]};
        float4 Fp[4], Fc[4];
        {
            const float* rb = feat1 + ((size_t)rows[0] * Xdim) * 32 + sub * 4;
#pragma unroll
            for (int c = 0; c < 4; ++c)
                Fp[c] = *(const float4*)(rb + (size_t)cols[c] * 32);
        }
#pragma unroll
        for (int i = 0; i < 3; ++i) {
            const float* rb = feat1 + ((size_t)rows[i + 1] * Xdim) * 32 + sub * 4;
#pragma unroll
            for (int c = 0; c < 4; ++c)
                Fc[c] = *(const float4*)(rb + (size_t)cols[c] * 32);
            float wyv = wy[i], omwy = 1.f - wyv;
#pragma unroll
            for (int j = 0; j < 3; ++j) {
                float wxv = wx[j], omwx = 1.f - wxv;
                float w00 = omwx * omwy, w01 = wxv * omwy;
                float w10 = omwx * wyv,  w11 = wxv * wyv;
                float4 a = Fp[j], b = Fp[j + 1], c = Fc[j], d = Fc[j + 1];
                float dx = f0.x - (a.x * w00 + b.x * w01 + c.x * w10 + d.x * w11);
                float dy = f0.y - (a.y * w00 + b.y * w01 + c.y * w10 + d.y * w11);
                float dz = f0.z - (a.z * w00 + b.z * w01 + c.z * w10 + d.z * w11);
                float dw = f0.w - (a.w * w00 + b.w * w01 + c.w * w10 + d.w * w11);
                cacc[i * 3 + j] = dx * dx + dy * dy + dz * dz + dw * dw;
            }
#pragma unroll
            for (int c = 0; c < 4; ++c) Fp[c] = Fc[c];
        }
    } else {
#pragma unroll
        for (int i = 0; i < 3; ++i) {
            float wyv = wy[i], omwy = 1.f - wyv;
            int rb0 = r0[i] * (Xdim * 32);
            int rb1 = r1[i] * (Xdim * 32);
#pragma unroll
            for (int j = 0; j < 3; ++j) {
                const float4 f00 = *(const float4*)(feat1 + rb0 + c0[j] * 32 + sub * 4);
                const float4 f01 = *(const float4*)(feat1 + rb0 + c1[j] * 32 + sub * 4);
                const float4 f10 = *(const float4*)(feat1 + rb1 + c0[j] * 32 + sub * 4);
                const float4 f11 = *(const float4*)(feat1 + rb1 + c1[j] * 32 + sub * 4);
                float wxv = wx[j], omwx = 1.f - wxv;
                float w00 = omwx * omwy, w01 = wxv * omwy;
                float w10 = omwx * wyv,  w11 = wxv * wyv;
                float dx = f0.x - (f00.x * w00 + f01.x * w01 + f10.x * w10 + f11.x * w11);
                float dy = f0.y - (f00.y * w00 + f01.y * w01 + f10.y * w10 + f11.y * w11);
                float dz = f0.z - (f00.z * w00 + f01.z * w01 + f10.z * w10 + f11.z * w11);
                float dw = f0.w - (f00.w * w00 + f01.w * w01 + f10.w * w10 + f11.w * w11);
                cacc[i * 3 + j] = dx * dx + dy * dy + dz * dz + dw * dw;
            }
        }
    }

#pragma unroll
    for (int m = 1; m <= 4; m <<= 1) {
#pragma unroll
        for (int k = 0; k < 9; ++k)
            cacc[k] += __shfl_xor(cacc[k], m);
    }
    if (sub == 0) {
#pragma unroll
        for (int k = 0; k < 9; ++k)
            cost_lds[g * 9 + k] = cacc[k];
    }
    __syncthreads();

    // Planar write: for fixed k, 32 consecutive pixels = 128B contiguous.
    {
        const int k = t >> 5, p = t & 31;             // k = 0..7
        cost[(size_t)k * NPIX + swz * 32 + p] = cost_lds[p * 9 + k];
        if (t < 32)
            cost[(size_t)8 * NPIX + swz * 32 + t] = cost_lds[t * 9 + 8];
    }
}

// ---------------- Kernel 2: softmax + 6x6 solve ----------------
// 1 thread per pixel, full 64-lane waves, coalesced planar cost reads.
__global__ __launch_bounds__(256, 4) void qf_solve_kernel(
    const float* __restrict__ cost,   // [9][NPIX]
    float* __restrict__ out)          // [NPIX][6]
{
    const int pix = blockIdx.x * 256 + threadIdx.x;

    float c[9];
#pragma unroll
    for (int k = 0; k < 9; ++k) c[k] = cost[(size_t)k * NPIX + pix];

    float cmin = c[0];
#pragma unroll
    for (int k = 1; k < 9; ++k) cmin = fminf(cmin, c[k]);

    float e[9], sumf = 0.f;
#pragma unroll
    for (int k = 0; k < 9; ++k) {
        e[k] = expf(cmin - c[k]);
        sumf += e[k];
    }
    float invs = 1.f / sumf;

    float w[9], q[9];
#pragma unroll
    for (int k = 0; k < 9; ++k) {
        w[k] = e[k] * invs;
        q[k] = w[k] * c[k];
    }

    float sc0 = w[0] + w[3] + w[6], sc2 = w[2] + w[5] + w[8];
    float sr0 = w[0] + w[1] + w[2], sr2 = w[6] + w[7] + w[8];
    float S10 = sc2 - sc0, S20 = sc2 + sc0;
    float S01 = sr2 - sr0, S02 = sr2 + sr0;
    float S11 = (w[0] + w[8]) - (w[2] + w[6]);
    float S21 = (w[6] + w[8]) - (w[0] + w[2]);
    float S12 = (w[2] + w[8]) - (w[0] + w[6]);
    float S22 = w[0] + w[2] + w[6] + w[8];
    float S00 = sr0 + w[3] + w[4] + w[5] + sr2;

    float qc0 = q[0] + q[3] + q[6], qc2 = q[2] + q[5] + q[8];
    float qr0 = q[0] + q[1] + q[2], qr2 = q[6] + q[7] + q[8];
    float T10 = qc2 - qc0, T20 = qc2 + qc0;
    float T01 = qr2 - qr0, T02 = qr2 + qr0;
    float T11 = (q[0] + q[8]) - (q[2] + q[6]);
    float T00 = qr0 + q[3] + q[4] + q[5] + qr2;

    double M[6][6], rhs[6], ip[6];
    M[0][0] = (double)S20 + EPS; M[0][1] = S22; M[0][2] = S11; M[0][3] = S10; M[0][4] = S21; M[0][5] = S20;
    M[1][1] = (double)S02 + EPS; M[1][2] = S11; M[1][3] = S12; M[1][4] = S01; M[1][5] = S02;
    M[2][2] = (double)S22 + EPS; M[2][3] = S21; M[2][4] = S12; M[2][5] = S11;
    M[3][3] = (double)S20 + EPS; M[3][4] = S11; M[3][5] = S10;
    M[4][4] = (double)S02 + EPS; M[4][5] = S01;
    M[5][5] = (double)S00 + EPS;
    rhs[0] = T20; rhs[1] = T02; rhs[2] = T11; rhs[3] = T10; rhs[4] = T01; rhs[5] = T00;

#pragma unroll
    for (int p = 0; p < 6; ++p) {
        ip[p] = fast_rcp64(M[p][p]);
#pragma unroll
        for (int r = p + 1; r < 6; ++r) {
            double f = M[p][r] * ip[p];
#pragma unroll
            for (int cc = r; cc < 6; ++cc)
                M[r][cc] -= f * M[p][cc];
            rhs[r] -= f * rhs[p];
        }
    }
    double sol[6];
#pragma unroll
    for (int p = 5; p >= 0; --p) {
        double s2 = rhs[p];
#pragma unroll
        for (int cc = p + 1; cc < 6; ++cc) s2 -= M[p][cc] * sol[cc];
        sol[p] = s2 * ip[p];
    }

#pragma unroll
    for (int i = 0; i < 6; ++i) out[(size_t)pix * 6 + i] = (float)sol[i];
}

// ---------------- Fallback: R15 fused kernel (if d_ws too small) ----------------
__global__ __launch_bounds__(256, 2) void qf_fused_kernel(
    const float* __restrict__ feat0,
    const float* __restrict__ feat1,
    const float* __restrict__ flow,
    float* __restrict__ out)
{
    __shared__ float cost_lds[PPB * 9];

    const int t   = threadIdx.x;
    const int g   = t >> 3;
    const int sub = t & 7;

#pragma unroll 1
    for (int it = 0; it < NITER; ++it) {
        const int pb  = it * 32 + g;
        const int pix = blockIdx.x * PPB + pb;
        const int y = pix >> 9;
        const int x = pix & (Xdim - 1);

        const float u = flow[pix * 3 + 0];
        const float v = flow[pix * 3 + 1];
        const float4 f0 = *(const float4*)(feat0 + (size_t)pix * 32 + sub * 4);

        const float pxc = (float)x + u;
        const float pyc = (float)y + v;

        int   c0[3], c1[3], r0[3], r1[3];
        float wx[3], wy[3];
#pragma unroll
        for (int j = 0; j < 3; ++j) {
            float px = pxc + (float)(j - 1);
            float fx = floorf(px);
            wx[j] = px - fx;
            int xi = min(max((int)fx, 0), Xdim - 1);
            c0[j] = xi;
            c1[j] = min(xi + 1, Xdim - 1);
            float py = pyc + (float)(j - 1);
            float fy = floorf(py);
            wy[j] = py - fy;
            int yi = min(max((int)fy, 0), Ydim - 1);
            r0[j] = yi;
            r1[j] = min(yi + 1, Ydim - 1);
        }

        float cacc[9];
        const bool fast = (c1[0] == c0[1]) & (c1[1] == c0[2])
                        & (r1[0] == r0[1]) & (r1[1] == r0[2]);

        if (fast) {
            const int cols[4] = {c0[0], c0[1], c0[2], c1[2]};
            const int rows[4] = {r0[0], r0[1], r0[2], r1[2]};
            float4 F[4][4];
#pragma unroll
            for (int r = 0; r < 4; ++r) {
                const float* rb = feat1 + ((size_t)rows[r] * Xdim) * 32 + sub * 4;
#pragma unroll
                for (int c = 0; c < 4; ++c)
                    F[r][c] = *(const float4*)(rb + (size_t)cols[c] * 32);
            }
#pragma unroll
            for (int r = 0; r < 4; ++r)
#pragma unroll
                for (int c = 0; c < 4; ++c)
                    asm volatile("" : "+v"(F[r][c].x), "+v"(F[r][c].y),
                                      "+v"(F[r][c].z), "+v"(F[r][c].w));
#pragma unroll
            for (int i = 0; i < 3; ++i) {
                float wyv = wy[i], omwy = 1.f - wyv;
#pragma unroll
                for (int j = 0; j < 3; ++j) {
                    float wxv = wx[j], omwx = 1.f - wxv;
                    float w00 = omwx * omwy, w01 = wxv * omwy;
                    float w10 = omwx * wyv,  w11 = wxv * wyv;
                    float4 a = F[i][j], b = F[i][j + 1], c = F[i + 1][j], d = F[i + 1][j + 1];
                    float dx = f0.x - (a.x * w00 + b.x * w01 + c.x * w10 + d.x * w11);
                    float dy = f0.y - (a.y * w00 + b.y * w01 + c.y * w10 + d.y * w11);
                    float dz = f0.z - (a.z * w00 + b.z * w01 + c.z * w10 + d.z * w11);
                    float dw = f0.w - (a.w * w00 + b.w * w01 + c.w * w10 + d.w * w11);
                    cacc[i * 3 + j] = dx * dx + dy * dy + dz * dz + dw * dw;
                }
            }
        } else {
#pragma unroll
            for (int i = 0; i < 3; ++i) {
                float wyv = wy[i], omwy = 1.f - wyv;
                int rb0 = r0[i] * (Xdim * 32);
                int rb1 = r1[i] * (Xdim * 32);
#pragma unroll
                for (int j = 0; j < 3; ++j) {
                    const float4 f00 = *(const float4*)(feat1 + rb0 + c0[j] * 32 + sub * 4);
                    const float4 f01 = *(const float4*)(feat1 + rb0 + c1[j] * 32 + sub * 4);
                    const float4 f10 = *(const float4*)(feat1 + rb1 + c0[j] * 32 + sub * 4);
                    const float4 f11 = *(const float4*)(feat1 + rb1 + c1[j] * 32 + sub * 4);
                    float wxv = wx[j], omwx = 1.f - wxv;
                    float w00 = omwx * omwy, w01 = wxv * omwy;
                    float w10 = omwx * wyv,  w11 = wxv * wyv;
                    float dx = f0.x - (f00.x * w00 + f01.x * w01 + f10.x * w10 + f11.x * w11);
                    float dy = f0.y - (f00.y * w00 + f01.y * w01 + f10.y * w10 + f11.y * w11);
                    float dz = f0.z - (f00.z * w00 + f01.z * w01 + f10.z * w10 + f11.z * w11);
                    float dw = f0.w - (f00.w * w00 + f01.w * w01 + f10.w * w10 + f11.w * w11);
                    cacc[i * 3 + j] = dx * dx + dy * dy + dz * dz + dw * dw;
                }
            }
        }

#pragma unroll
        for (int m = 1; m <= 4; m <<= 1) {
#pragma unroll
            for (int k = 0; k < 9; ++k)
                cacc[k] += __shfl_xor(cacc[k], m);
        }
        if (sub == 0) {
#pragma unroll
            for (int k = 0; k < 9; ++k)
                cost_lds[pb * 9 + k] = cacc[k];
        }
    }
    __syncthreads();

    const int lane = t & 63;
    if (lane < 32) {
        const int pb = (t >> 6) * 32 + lane;

        float c[9];
#pragma unroll
        for (int k = 0; k < 9; ++k) c[k] = cost_lds[pb * 9 + k];

        float cmin = c[0];
#pragma unroll
        for (int k = 1; k < 9; ++k) cmin = fminf(cmin, c[k]);

        float e[9], sumf = 0.f;
#pragma unroll
        for (int k = 0; k < 9; ++k) {
            e[k] = expf(cmin - c[k]);
            sumf += e[k];
        }
        float invs = 1.f / sumf;

        float w[9], q[9];
#pragma unroll
        for (int k = 0; k < 9; ++k) {
            w[k] = e[k] * invs;
            q[k] = w[k] * c[k];
        }

        float sc0 = w[0] + w[3] + w[6], sc2 = w[2] + w[5] + w[8];
        float sr0 = w[0] + w[1] + w[2], sr2 = w[6] + w[7] + w[8];
        float S10 = sc2 - sc0, S20 = sc2 + sc0;
        float S01 = sr2 - sr0, S02 = sr2 + sr0;
        float S11 = (w[0] + w[8]) - (w[2] + w[6]);
        float S21 = (w[6] + w[8]) - (w[0] + w[2]);
        float S12 = (w[2] + w[8]) - (w[0] + w[6]);
        float S22 = w[0] + w[2] + w[6] + w[8];
        float S00 = sr0 + w[3] + w[4] + w[5] + sr2;

        float qc0 = q[0] + q[3] + q[6], qc2 = q[2] + q[5] + q[8];
        float qr0 = q[0] + q[1] + q[2], qr2 = q[6] + q[7] + q[8];
        float T10 = qc2 - qc0, T20 = qc2 + qc0;
        float T01 = qr2 - qr0, T02 = qr2 + qr0;
        float T11 = (q[0] + q[8]) - (q[2] + q[6]);
        float T00 = qr0 + q[3] + q[4] + q[5] + qr2;

        double M[6][6], rhs[6], ip[6];
        M[0][0] = (double)S20 + EPS; M[0][1] = S22; M[0][2] = S11; M[0][3] = S10; M[0][4] = S21; M[0][5] = S20;
        M[1][1] = (double)S02 + EPS; M[1][2] = S11; M[1][3] = S12; M[1][4] = S01; M[1][5] = S02;
        M[2][2] = (double)S22 + EPS; M[2][3] = S21; M[2][4] = S12; M[2][5] = S11;
        M[3][3] = (double)S20 + EPS; M[3][4] = S11; M[3][5] = S10;
        M[4][4] = (double)S02 + EPS; M[4][5] = S01;
        M[5][5] = (double)S00 + EPS;
        rhs[0] = T20; rhs[1] = T02; rhs[2] = T11; rhs[3] = T10; rhs[4] = T01; rhs[5] = T00;

#pragma unroll
        for (int p = 0; p < 6; ++p) {
            ip[p] = fast_rcp64(M[p][p]);
#pragma unroll
            for (int r = p + 1; r < 6; ++r) {
                double f = M[p][r] * ip[p];
#pragma unroll
                for (int cc = r; cc < 6; ++cc)
                    M[r][cc] -= f * M[p][cc];
                rhs[r] -= f * rhs[p];
            }
        }
        double sol[6];
#pragma unroll
        for (int p = 5; p >= 0; --p) {
            double s2 = rhs[p];
#pragma unroll
            for (int cc = p + 1; cc < 6; ++cc) s2 -= M[p][cc] * sol[cc];
            sol[p] = s2 * ip[p];
        }

        const int opix = blockIdx.x * PPB + pb;
#pragma unroll
        for (int i = 0; i < 6; ++i) out[(size_t)opix * 6 + i] = (float)sol[i];
    }
}

extern "C" void kernel_launch(void* const* d_in, const int* in_sizes, int n_in,
                              void* d_out, int out_size, void* d_ws, size_t ws_size,
                              hipStream_t stream) {
    const float* feat0 = (const float*)d_in[0];
    const float* feat1 = (const float*)d_in[1];
    const float* flow  = (const float*)d_in[2];
    float* out = (float*)d_out;

    const size_t need = (size_t)9 * NPIX * sizeof(float);   // 7.08 MB
    if (d_ws != nullptr && ws_size >= need) {
        float* cost = (float*)d_ws;
        qf_cost_kernel<<<dim3(NBLK), dim3(256), 0, stream>>>(feat0, feat1, flow, cost);
        qf_solve_kernel<<<dim3(NPIX / 256), dim3(256), 0, stream>>>(cost, out);
    } else {
        qf_fused_kernel<<<dim3(NPIX / PPB), dim3(256), 0, stream>>>(feat0, feat1, flow, out);
    }
}

// Round 21
// 105.162 us; speedup vs baseline: 2.2049x; 2.1642x over previous
//
#include <hip/hip_runtime.h>
#include <math.h>

#define Ydim 384
#define Xdim 512
#define NPIX (Ydim * Xdim)
#define EPS 1e-4
#define PPB 128              // pixels per block
#define NITER (PPB / 32)     // cost-phase iterations (32 pixels each)

__device__ __forceinline__ double fast_rcp64(double d) {
    // approx fp32 rcp + 2 fp64 Newton steps -> ~full fp64 accuracy, no IEEE div
    double r = (double)__builtin_amdgcn_rcpf((float)d);
    r = r * (2.0 - d * r);
    r = r * (2.0 - d * r);
    return r;
}

// R21 = R15 fused kernel (best measured: scored 107.0) + full-wave solve.
// Revert rationale: split-kernel config measured 155us cost + re-poison
// entanglement (FETCH 170MB regardless of XCD swizzle, WRITE 283MB
// attributed vs 7MB written) -> d_ws path abandoned per R19 commitment.
// Solve change: threads 0..127 solve one pixel each (2 fully-active waves,
// waves 2-3 exit) instead of lanes<32 of all 4 waves (half-masked issue).
// Halves solve-phase issue cycles; numerics bit-identical.
__global__ __launch_bounds__(256, 2) void qf_fused_kernel(
    const float* __restrict__ feat0,
    const float* __restrict__ feat1,
    const float* __restrict__ flow,
    float* __restrict__ out)    // (NPIX, 6)
{
    __shared__ float cost_lds[PPB * 9];

    const int t   = threadIdx.x;
    const int g   = t >> 3;          // pixel group within 32-pixel slab
    const int sub = t & 7;           // 4 channels per lane

#pragma unroll 1
    for (int it = 0; it < NITER; ++it) {
        const int pb  = it * 32 + g;            // pixel index within block
        const int pix = blockIdx.x * PPB + pb;
        const int y = pix >> 9;                  // X = 512
        const int x = pix & (Xdim - 1);

        const float u = flow[pix * 3 + 0];
        const float v = flow[pix * 3 + 1];
        const float4 f0 = *(const float4*)(feat0 + (size_t)pix * 32 + sub * 4);

        // Reference op order exactly: px = ((x+u)) + (j-1), per-tap floor/clip.
        const float pxc = (float)x + u;
        const float pyc = (float)y + v;

        int   c0[3], c1[3], r0[3], r1[3];
        float wx[3], wy[3];
#pragma unroll
        for (int j = 0; j < 3; ++j) {
            float px = pxc + (float)(j - 1);
            float fx = floorf(px);
            wx[j] = px - fx;
            int xi = min(max((int)fx, 0), Xdim - 1);
            c0[j] = xi;
            c1[j] = min(xi + 1, Xdim - 1);
            float py = pyc + (float)(j - 1);
            float fy = floorf(py);
            wy[j] = py - fy;
            int yi = min(max((int)fy, 0), Ydim - 1);
            r0[j] = yi;
            r1[j] = min(yi + 1, Ydim - 1);
        }

        float cacc[9];
        const bool fast = (c1[0] == c0[1]) & (c1[1] == c0[2])
                        & (r1[0] == r0[1]) & (r1[1] == r0[2]);

        if (fast) {
            // 4x4 unique corner grid: issue ALL 16 loads, then pin every
            // loaded component (tied "+v") so the bilinear math consumes the
            // asm results and cannot be interleaved upward into the loads.
            const int cols[4] = {c0[0], c0[1], c0[2], c1[2]};
            const int rows[4] = {r0[0], r0[1], r0[2], r1[2]};
            float4 F[4][4];
#pragma unroll
            for (int r = 0; r < 4; ++r) {
                const float* rb = feat1 + ((size_t)rows[r] * Xdim) * 32 + sub * 4;
#pragma unroll
                for (int c = 0; c < 4; ++c)
                    F[r][c] = *(const float4*)(rb + (size_t)cols[c] * 32);
            }
#pragma unroll
            for (int r = 0; r < 4; ++r)
#pragma unroll
                for (int c = 0; c < 4; ++c)
                    asm volatile("" : "+v"(F[r][c].x), "+v"(F[r][c].y),
                                      "+v"(F[r][c].z), "+v"(F[r][c].w));
#pragma unroll
            for (int i = 0; i < 3; ++i) {
                float wyv = wy[i], omwy = 1.f - wyv;
#pragma unroll
                for (int j = 0; j < 3; ++j) {
                    float wxv = wx[j], omwx = 1.f - wxv;
                    float w00 = omwx * omwy, w01 = wxv * omwy;
                    float w10 = omwx * wyv,  w11 = wxv * wyv;
                    float4 a = F[i][j], b = F[i][j + 1], c = F[i + 1][j], d = F[i + 1][j + 1];
                    float dx = f0.x - (a.x * w00 + b.x * w01 + c.x * w10 + d.x * w11);
                    float dy = f0.y - (a.y * w00 + b.y * w01 + c.y * w10 + d.y * w11);
                    float dz = f0.z - (a.z * w00 + b.z * w01 + c.z * w10 + d.z * w11);
                    float dw = f0.w - (a.w * w00 + b.w * w01 + c.w * w10 + d.w * w11);
                    cacc[i * 3 + j] = dx * dx + dy * dy + dz * dz + dw * dw;
                }
            }
        } else {
            // Border / binade-edge pixels: exact per-tap 36-load path.
#pragma unroll
            for (int i = 0; i < 3; ++i) {
                float wyv = wy[i], omwy = 1.f - wyv;
                int rb0 = r0[i] * (Xdim * 32);
                int rb1 = r1[i] * (Xdim * 32);
#pragma unroll
                for (int j = 0; j < 3; ++j) {
                    const float4 f00 = *(const float4*)(feat1 + rb0 + c0[j] * 32 + sub * 4);
                    const float4 f01 = *(const float4*)(feat1 + rb0 + c1[j] * 32 + sub * 4);
                    const float4 f10 = *(const float4*)(feat1 + rb1 + c0[j] * 32 + sub * 4);
                    const float4 f11 = *(const float4*)(feat1 + rb1 + c1[j] * 32 + sub * 4);
                    float wxv = wx[j], omwx = 1.f - wxv;
                    float w00 = omwx * omwy, w01 = wxv * omwy;
                    float w10 = omwx * wyv,  w11 = wxv * wyv;
                    float dx = f0.x - (f00.x * w00 + f01.x * w01 + f10.x * w10 + f11.x * w11);
                    float dy = f0.y - (f00.y * w00 + f01.y * w01 + f10.y * w10 + f11.y * w11);
                    float dz = f0.z - (f00.z * w00 + f01.z * w01 + f10.z * w10 + f11.z * w11);
                    float dw = f0.w - (f00.w * w00 + f01.w * w01 + f10.w * w10 + f11.w * w11);
                    cacc[i * 3 + j] = dx * dx + dy * dy + dz * dz + dw * dw;
                }
            }
        }

        // Reduce over the 8 lanes of the subgroup.
#pragma unroll
        for (int m = 1; m <= 4; m <<= 1) {
#pragma unroll
            for (int k = 0; k < 9; ++k)
                cacc[k] += __shfl_xor(cacc[k], m);
        }
        if (sub == 0) {
#pragma unroll
            for (int k = 0; k < 9; ++k)
                cost_lds[pb * 9 + k] = cacc[k];
        }
    }
    __syncthreads();

    // ---- Solve phase: threads 0..127, one pixel each. Waves 0-1 are
    // FULLY active (no half exec mask); waves 2-3 exit and free their
    // SIMDs. LDS reads stride 9 floats/lane -> 2-way bank alias (free). ----
    if (t < PPB) {
        const int pb = t;

        float c[9];
#pragma unroll
        for (int k = 0; k < 9; ++k) c[k] = cost_lds[pb * 9 + k];

        float cmin = c[0];
#pragma unroll
        for (int k = 1; k < 9; ++k) cmin = fminf(cmin, c[k]);

        float e[9], sumf = 0.f;
#pragma unroll
        for (int k = 0; k < 9; ++k) {
            e[k] = expf(cmin - c[k]);
            sumf += e[k];
        }
        float invs = 1.f / sumf;

        float w[9], q[9];
#pragma unroll
        for (int k = 0; k < 9; ++k) {
            w[k] = e[k] * invs;
            q[k] = w[k] * c[k];
        }

        // Moments (fp32, same precision class as reference's fp32 einsum).
        float sc0 = w[0] + w[3] + w[6], sc2 = w[2] + w[5] + w[8];
        float sr0 = w[0] + w[1] + w[2], sr2 = w[6] + w[7] + w[8];
        float S10 = sc2 - sc0, S20 = sc2 + sc0;
        float S01 = sr2 - sr0, S02 = sr2 + sr0;
        float S11 = (w[0] + w[8]) - (w[2] + w[6]);
        float S21 = (w[6] + w[8]) - (w[0] + w[2]);
        float S12 = (w[2] + w[8]) - (w[0] + w[6]);
        float S22 = w[0] + w[2] + w[6] + w[8];
        float S00 = sr0 + w[3] + w[4] + w[5] + sr2;

        float qc0 = q[0] + q[3] + q[6], qc2 = q[2] + q[5] + q[8];
        float qr0 = q[0] + q[1] + q[2], qr2 = q[6] + q[7] + q[8];
        float T10 = qc2 - qc0, T20 = qc2 + qc0;
        float T01 = qr2 - qr0, T02 = qr2 + qr0;
        float T11 = (q[0] + q[8]) - (q[2] + q[6]);
        float T00 = qr0 + q[3] + q[4] + q[5] + qr2;

        // fp64 symmetric elimination (SPD + eps), upper triangle only.
        double M[6][6], rhs[6], ip[6];
        M[0][0] = (double)S20 + EPS; M[0][1] = S22; M[0][2] = S11; M[0][3] = S10; M[0][4] = S21; M[0][5] = S20;
        M[1][1] = (double)S02 + EPS; M[1][2] = S11; M[1][3] = S12; M[1][4] = S01; M[1][5] = S02;
        M[2][2] = (double)S22 + EPS; M[2][3] = S21; M[2][4] = S12; M[2][5] = S11;
        M[3][3] = (double)S20 + EPS; M[3][4] = S11; M[3][5] = S10;
        M[4][4] = (double)S02 + EPS; M[4][5] = S01;
        M[5][5] = (double)S00 + EPS;
        rhs[0] = T20; rhs[1] = T02; rhs[2] = T11; rhs[3] = T10; rhs[4] = T01; rhs[5] = T00;

#pragma unroll
        for (int p = 0; p < 6; ++p) {
            ip[p] = fast_rcp64(M[p][p]);
#pragma unroll
            for (int r = p + 1; r < 6; ++r) {
                double f = M[p][r] * ip[p];
#pragma unroll
                for (int cc = r; cc < 6; ++cc)
                    M[r][cc] -= f * M[p][cc];
                rhs[r] -= f * rhs[p];
            }
        }
        double sol[6];
#pragma unroll
        for (int p = 5; p >= 0; --p) {
            double s2 = rhs[p];
#pragma unroll
            for (int cc = p + 1; cc < 6; ++cc) s2 -= M[p][cc] * sol[cc];
            sol[p] = s2 * ip[p];
        }

        const int opix = blockIdx.x * PPB + pb;
#pragma unroll
        for (int i = 0; i < 6; ++i) out[(size_t)opix * 6 + i] = (float)sol[i];
    }
}

extern "C" void kernel_launch(void* const* d_in, const int* in_sizes, int n_in,
                              void* d_out, int out_size, void* d_ws, size_t ws_size,
                              hipStream_t stream) {
    const float* feat0 = (const float*)d_in[0];
    const float* feat1 = (const float*)d_in[1];
    const float* flow  = (const float*)d_in[2];
    float* out = (float*)d_out;

    qf_fused_kernel<<<dim3(NPIX / PPB), dim3(256), 0, stream>>>(feat0, feat1, flow, out);
}